// Round 2
// baseline (9967.696 us; speedup 1.0000x reference)
//
#include <hip/hip_runtime.h>

typedef short short8 __attribute__((ext_vector_type(8)));
typedef float f32x4 __attribute__((ext_vector_type(4)));

#define NB 64
#define NT 1024
#define NI 128
#define NH 512

__device__ __forceinline__ unsigned short f2bf(float f) {
  union { float f; unsigned u; } v; v.f = f;
  unsigned u = v.u;
  return (unsigned short)((u + 0x7FFFu + ((u >> 16) & 1u)) >> 16);
}

__device__ __forceinline__ f32x4 mfma16(short8 a, short8 b, f32x4 c) {
  return __builtin_amdgcn_mfma_f32_16x16x32_bf16(a, b, c, 0, 0, 0);
}

// Build combined recurrent matrix M[o][k] (512x512 bf16), scales folded in.
// rows o<256:  A1*W11[o,k]        | A1*0.5*W21[o,k-256]
// rows o>=256: A1*0.5*W12[o-256,k]| A1*W22[o-256,k-256]
__global__ __launch_bounds__(256) void buildM_k(
    const float* __restrict__ W11, const float* __restrict__ W22,
    const float* __restrict__ W12, const float* __restrict__ W21,
    unsigned short* __restrict__ M) {
  int idx = blockIdx.x * 256 + threadIdx.x;  // 262144 total
  int o = idx >> 9, k = idx & 511;
  const float A1f = (float)(16.67 / 100.0);
  float v;
  if (o < 256) {
    v = (k < 256) ? A1f * W11[(o << 8) + k]
                  : A1f * 0.5f * W21[(o << 8) + (k - 256)];
  } else {
    int o2 = o - 256;
    v = (k < 256) ? A1f * 0.5f * W12[(o2 << 8) + k]
                  : A1f * W22[(o2 << 8) + (k - 256)];
  }
  M[idx] = f2bf(v);
}

__global__ __launch_bounds__(256) void buildWiT_k(const float* __restrict__ Wi,
                                                  float* __restrict__ WiT) {
  int idx = blockIdx.x * 256 + threadIdx.x;  // 32768 = 128*256, WiT[k][o]
  int k = idx >> 8, o = idx & 255;
  WiT[idx] = Wi[o * 128 + k];
}

// xp'[t][b][o] = A1 * (sum_i x[b][t][i]*Wi[o][i] + bi[o]), f32, layout [t][b][o].
__global__ __launch_bounds__(256) void xproj_k(
    const float* __restrict__ x, const float* __restrict__ WiT,
    const float* __restrict__ bi, float* __restrict__ xp) {
  __shared__ float xs[128 * 68];  // x transposed [k][r], pad 68 for banks
  int tid = threadIdx.x;
  int wv = tid >> 6;   // 0..3 row-group (16 rows each)
  int c = tid & 63;    // col-group: cols 4c..4c+3
  long Rbase = (long)blockIdx.x * 64;
  const float* xg = x + Rbase * 128;
  #pragma unroll
  for (int i = 0; i < 32; i++) {
    int idx = tid + 256 * i;       // idx = r*128 + k
    int r = idx >> 7, k = idx & 127;
    xs[k * 68 + r] = xg[idx];
  }
  __syncthreads();
  float acc[4][16];
  #pragma unroll
  for (int a = 0; a < 4; a++)
    #pragma unroll
    for (int b = 0; b < 16; b++) acc[a][b] = 0.f;
  for (int k = 0; k < 128; k++) {
    f32x4 w4 = *(const f32x4*)(WiT + k * 256 + 4 * c);
    const float* xr = &xs[k * 68 + 16 * wv];
    #pragma unroll
    for (int rr = 0; rr < 4; rr++) {
      f32x4 xv = *(const f32x4*)(xr + 4 * rr);
      #pragma unroll
      for (int cc = 0; cc < 4; cc++) {
        #pragma unroll
        for (int u = 0; u < 4; u++)
          acc[cc][4 * rr + u] = fmaf(w4[cc], xv[u], acc[cc][4 * rr + u]);
      }
    }
  }
  f32x4 bv = *(const f32x4*)(bi + 4 * c);
  const float A1f = (float)(16.67 / 100.0);
  #pragma unroll
  for (int rr = 0; rr < 16; rr++) {
    long R = Rbase + 16 * wv + rr;
    int b = (int)(R >> 10), t = (int)(R & 1023);
    f32x4 o;
    #pragma unroll
    for (int cc = 0; cc < 4; cc++) o[cc] = A1f * (acc[cc][rr] + bv[cc]);
    *(f32x4*)(xp + ((long)(t * 64 + b) << 8) + 4 * c) = o;
  }
}

// Recurrent kernel: 4 blocks x 512 threads (8 waves, 2/SIMD).
// Block g: batches 16g..16g+15 (the MFMA m-dim). Wave w: output cols [64w,64w+64).
// ALL 16 k-tiles of M pinned in registers (256 VGPR/wave of weights; RF = 2MB/CU).
// h double-buffered in LDS (bf16, XOR-swizzled). Raw lgkm-only barrier per step
// so xp prefetch loads + output stores stay in flight across steps.
__global__ __launch_bounds__(512, 1) void rnn_k(
    const unsigned short* __restrict__ M, const float* __restrict__ xp,
    float* __restrict__ out) {
  const int g = blockIdx.x;
  const int tid = threadIdx.x;
  const int w = tid >> 6;
  const int lane = tid & 63;
  const int n = lane & 15;   // B col within tile / A row (batch)
  const int q = lane >> 4;   // 0..3

  __shared__ __align__(16) unsigned short hb[2][16 * 512];
  #pragma unroll
  for (int i = 0; i < 16; i++) hb[0][tid + 512 * i] = 0;

  const float C1 = (float)(1.0 - 16.67 / 100.0);

  // fully pinned B fragments: Bp[nt][kt] = M[row = w*64+nt*16+n][kt*32 + q*8 ..+8]
  short8 Bp[4][16];
  #pragma unroll
  for (int nt = 0; nt < 4; nt++) {
    const unsigned short* mb = M + (w * 64 + nt * 16 + n) * 512 + q * 8;
    #pragma unroll
    for (int kt = 0; kt < 16; kt++) Bp[nt][kt] = *(const short8*)(mb + kt * 32);
  }

  float hprev[4][4];
  #pragma unroll
  for (int a = 0; a < 4; a++)
    #pragma unroll
    for (int b = 0; b < 4; b++) hprev[a][b] = 0.f;

  // xp only feeds area-1 columns (cols 0..255 -> waves 0..3)
  const bool hasxp = (w < 4);
  const float* xpb = xp + ((g * 16 + 4 * q) << 8) + w * 64 + n;
  float xpA[4][4], xpB[4][4];  // double-buffer: even t uses A, odd t uses B
  #pragma unroll
  for (int a = 0; a < 4; a++)
    #pragma unroll
    for (int b = 0; b < 4; b++) { xpA[a][b] = 0.f; xpB[a][b] = 0.f; }
  if (hasxp) {
    #pragma unroll
    for (int nt = 0; nt < 4; nt++)
      #pragma unroll
      for (int j = 0; j < 4; j++) {
        xpA[nt][j] = __builtin_nontemporal_load(xpb + 0L * 16384 + j * 256 + nt * 16);
        xpB[nt][j] = __builtin_nontemporal_load(xpb + 1L * 16384 + j * 256 + nt * 16);
      }
  }

  float* outb = out + (long)(g * 16 + 4 * q) * (NT * NH) + w * 64 + n;

  __syncthreads();  // once: h-init visible + pinned weights arriving

  // one step: read hr, write hw, use/refill xpc (refill targets t+2)
  auto step = [&](const unsigned short* __restrict__ hr,
                  unsigned short* __restrict__ hw, int t,
                  float (&xpc)[4][4]) {
    f32x4 acc[4];
    #pragma unroll
    for (int nt = 0; nt < 4; nt++) acc[nt] = (f32x4){0.f, 0.f, 0.f, 0.f};

    #pragma unroll
    for (int kt = 0; kt < 16; kt++) {
      unsigned e = (unsigned)((n * 512 + kt * 32 + q * 8) ^ ((n & 7) << 3));
      short8 a = *(const short8*)(hr + e);
      #pragma unroll
      for (int nt = 0; nt < 4; nt++) acc[nt] = mfma16(a, Bp[nt][kt], acc[nt]);
    }

    float* outt = outb + t * NH;
    int tn = t + 2; if (tn >= NT) tn = 0;   // wrap: values unused, stay valid
    const float* xpl = xpb + (long)tn * 16384;

    #pragma unroll
    for (int nt = 0; nt < 4; nt++) {
      #pragma unroll
      for (int j = 0; j < 4; j++) {
        float v = fmaf(hprev[nt][j], C1, acc[nt][j] + xpc[nt][j]);
        v = fmaxf(v, 0.f);
        hprev[nt][j] = v;
        __builtin_nontemporal_store(v, outt + (long)j * (NT * NH) + nt * 16);
        unsigned rr;
        asm("v_cvt_pk_bf16_f32 %0, %1, %2" : "=v"(rr) : "v"(v), "v"(v));
        int mm = 4 * q + j;
        int col = w * 64 + nt * 16 + n;
        hw[(unsigned)((mm * 512 + col) ^ ((mm & 7) << 3))] = (unsigned short)rr;
        if (hasxp)
          xpc[nt][j] = __builtin_nontemporal_load(xpl + j * 256 + nt * 16);
      }
    }
    // LDS-only drain + barrier: vmem (stores + xp prefetch) stays in flight
    asm volatile("s_waitcnt lgkmcnt(0)\n\ts_barrier" ::: "memory");
  };

  #pragma unroll 1
  for (int t = 0; t < NT; t += 2) {
    step(hb[0], hb[1], t, xpA);
    step(hb[1], hb[0], t + 1, xpB);
  }

  // final h1, h2
  const long fbase = (long)NB * NT * NH;  // 33554432
  #pragma unroll
  for (int nt = 0; nt < 4; nt++) {
    #pragma unroll
    for (int j = 0; j < 4; j++) {
      int b = g * 16 + 4 * q + j;
      int col = w * 64 + nt * 16 + n;
      long off = (col < 256) ? (fbase + b * 256 + col)
                             : (fbase + 16384 + b * 256 + (col - 256));
      out[off] = hprev[nt][j];
    }
  }
}

extern "C" void kernel_launch(void* const* d_in, const int* in_sizes, int n_in,
                              void* d_out, int out_size, void* d_ws, size_t ws_size,
                              hipStream_t stream) {
  const float* x   = (const float*)d_in[0];
  // d_in[1] = seq_lengths: forward-identity masking, unused
  const float* Wi  = (const float*)d_in[2];
  const float* bi  = (const float*)d_in[3];
  const float* W11 = (const float*)d_in[4];
  const float* W22 = (const float*)d_in[5];
  const float* W12 = (const float*)d_in[6];
  const float* W21 = (const float*)d_in[7];
  float* out = (float*)d_out;

  unsigned short* M = (unsigned short*)d_ws;                 // 512 KB
  float* WiT = (float*)((char*)d_ws + (512 << 10));          // 128 KB
  float* xp  = (float*)((char*)d_ws + (1 << 20));            // 64 MB

  buildM_k<<<1024, 256, 0, stream>>>(W11, W22, W12, W21, M);
  buildWiT_k<<<128, 256, 0, stream>>>(Wi, WiT);
  xproj_k<<<1024, 256, 0, stream>>>(x, WiT, bi, xp);
  rnn_k<<<4, 512, 0, stream>>>(M, xp, out);
}

// Round 3
// 2880.644 us; speedup vs baseline: 3.4602x; 3.4602x over previous
//
#include <hip/hip_runtime.h>

typedef short short8 __attribute__((ext_vector_type(8)));
typedef float f32x4 __attribute__((ext_vector_type(4)));

#define NB 64
#define NT 1024
#define NI 128
#define NH 512

// ws layout (bytes):
//   0        : M      512KB  (combined recurrent matrix, bf16 [512][512])
//   524288   : WiT    128KB
//   655360   : X      128KB  exchange: [g][p][wl][tb] * 2048B, lane*32B inside
//   786432   : flags  2KB    [g][p][wl] * 16 uints (64B stride)
//   790528   : xcc    64B    per-bid xcc-id table (16 ints)
//   1048576  : xp     64MB   [t][b][256] f32
#define WS_X     655360
#define WS_FLAGS 786432
#define WS_XCC   790528
#define WS_XP    1048576

__device__ __forceinline__ unsigned short f2bf(float f) {
  union { float f; unsigned u; } v; v.f = f;
  unsigned u = v.u;
  return (unsigned short)((u + 0x7FFFu + ((u >> 16) & 1u)) >> 16);
}

__device__ __forceinline__ f32x4 mfma16(short8 a, short8 b, f32x4 c) {
  return __builtin_amdgcn_mfma_f32_16x16x32_bf16(a, b, c, 0, 0, 0);
}

__device__ __forceinline__ float bflo(unsigned d) {
  union { unsigned u; float f; } v; v.u = d << 16; return v.f;
}
__device__ __forceinline__ float bfhi(unsigned d) {
  union { unsigned u; float f; } v; v.u = d & 0xFFFF0000u; return v.f;
}

// Build combined recurrent matrix M[o][k] (512x512 bf16), scales folded in.
// Also zeroes the flag/xcc region (stream-ordered before rnn_k: replay-safe).
__global__ __launch_bounds__(256) void buildM_k(
    const float* __restrict__ W11, const float* __restrict__ W22,
    const float* __restrict__ W12, const float* __restrict__ W21,
    unsigned short* __restrict__ M, unsigned* __restrict__ ctrl) {
  if (blockIdx.x == 0) {
    #pragma unroll
    for (int i = 0; i < 8; i++) ctrl[threadIdx.x + 256 * i] = 0;  // 8KB
  }
  int idx = blockIdx.x * 256 + threadIdx.x;  // 262144 total
  int o = idx >> 9, k = idx & 511;
  const float A1f = (float)(16.67 / 100.0);
  float v;
  if (o < 256) {
    v = (k < 256) ? A1f * W11[(o << 8) + k]
                  : A1f * 0.5f * W21[(o << 8) + (k - 256)];
  } else {
    int o2 = o - 256;
    v = (k < 256) ? A1f * 0.5f * W12[(o2 << 8) + k]
                  : A1f * W22[(o2 << 8) + (k - 256)];
  }
  M[idx] = f2bf(v);
}

__global__ __launch_bounds__(256) void buildWiT_k(const float* __restrict__ Wi,
                                                  float* __restrict__ WiT) {
  int idx = blockIdx.x * 256 + threadIdx.x;  // 32768 = 128*256, WiT[k][o]
  int k = idx >> 8, o = idx & 255;
  WiT[idx] = Wi[o * 128 + k];
}

// xp'[t][b][o] = A1 * (sum_i x[b][t][i]*Wi[o][i] + bi[o]), f32, layout [t][b][o].
__global__ __launch_bounds__(256) void xproj_k(
    const float* __restrict__ x, const float* __restrict__ WiT,
    const float* __restrict__ bi, float* __restrict__ xp) {
  __shared__ float xs[128 * 68];
  int tid = threadIdx.x;
  int wv = tid >> 6;
  int c = tid & 63;
  long Rbase = (long)blockIdx.x * 64;
  const float* xg = x + Rbase * 128;
  #pragma unroll
  for (int i = 0; i < 32; i++) {
    int idx = tid + 256 * i;
    int r = idx >> 7, k = idx & 127;
    xs[k * 68 + r] = xg[idx];
  }
  __syncthreads();
  float acc[4][16];
  #pragma unroll
  for (int a = 0; a < 4; a++)
    #pragma unroll
    for (int b = 0; b < 16; b++) acc[a][b] = 0.f;
  for (int k = 0; k < 128; k++) {
    f32x4 w4 = *(const f32x4*)(WiT + k * 256 + 4 * c);
    const float* xr = &xs[k * 68 + 16 * wv];
    #pragma unroll
    for (int rr = 0; rr < 4; rr++) {
      f32x4 xv = *(const f32x4*)(xr + 4 * rr);
      #pragma unroll
      for (int cc = 0; cc < 4; cc++) {
        #pragma unroll
        for (int u = 0; u < 4; u++)
          acc[cc][4 * rr + u] = fmaf(w4[cc], xv[u], acc[cc][4 * rr + u]);
      }
    }
  }
  f32x4 bv = *(const f32x4*)(bi + 4 * c);
  const float A1f = (float)(16.67 / 100.0);
  #pragma unroll
  for (int rr = 0; rr < 16; rr++) {
    long R = Rbase + 16 * wv + rr;
    int b = (int)(R >> 10), t = (int)(R & 1023);
    f32x4 o;
    #pragma unroll
    for (int cc = 0; cc < 4; cc++) o[cc] = A1f * (acc[cc][rr] + bv[cc]);
    *(f32x4*)(xp + ((long)(t * 64 + b) << 8) + 4 * c) = o;
  }
}

// Recurrent kernel, k-split pair design.
// grid = 16; active bids: {0..3} role 0 (k in [0,256)), {8..11} role 1 (k in [256,512)).
// bids {4..7, 12..15} exit (pairing (g, g+8) -> same XCD under bid%8 round-robin).
// Block (g, r): batches 16g..16g+15; holds B-frags for ALL 512 out-cols over its
// 256-k half (128 VGPR/wave). Waves [4r,4r+4) = "consume" (finalize own cols =
// own k-half's h); other 4 waves = "ship" (send partials to partner via L2/L3).
__global__ __launch_bounds__(512, 2) void rnn_k(
    const unsigned short* __restrict__ M, const float* __restrict__ xp,
    float* __restrict__ out, char* __restrict__ ws) {
  const int bid = blockIdx.x;
  if (bid & 4) return;
  const int g = bid & 3;
  const int role = bid >> 3;
  const int tid = threadIdx.x;
  const int w = tid >> 6;
  const int lane = tid & 63;
  const int n = lane & 15;
  const int q = lane >> 4;
  const bool isCons = ((w >> 2) == role);   // waves [4r, 4r+4) finalize
  const int wl = w & 3;

  __shared__ __align__(16) unsigned short hb[2][16 * 256];  // [batch][k-local]
  __shared__ int sFast;

  {  // zero hb[0] (t=0 h state)
    int4 z = {0, 0, 0, 0};
    ((int4*)&hb[0][0])[tid] = z;  // 512 * 16B = 8KB
  }

  unsigned* flags = (unsigned*)(ws + WS_FLAGS);
  unsigned* xcct = (unsigned*)(ws + WS_XCC);
  if (tid == 0) {
    unsigned myx;
    asm volatile("s_getreg_b32 %0, hwreg(HW_REG_XCC_ID)" : "=s"(myx));
    __hip_atomic_store(&xcct[bid], myx + 1, __ATOMIC_RELAXED, __HIP_MEMORY_SCOPE_AGENT);
    unsigned ox;
    while ((ox = __hip_atomic_load(&xcct[bid ^ 8], __ATOMIC_RELAXED,
                                   __HIP_MEMORY_SCOPE_AGENT)) == 0u)
      __builtin_amdgcn_s_sleep(2);
    sFast = (ox == myx + 1) ? 1 : 0;
  }

  const int kbase = role << 8;  // element offset of this block's k-half
  const float C1 = (float)(1.0 - 16.67 / 100.0);

  // pinned B fragments: Bp[nt][kt] = M[col = w*64+nt*16+n][kbase + kt*32 + q*8 ..+8]
  short8 Bp[4][8];
  #pragma unroll
  for (int nt = 0; nt < 4; nt++) {
    const unsigned short* mb = M + (w * 64 + nt * 16 + n) * 512 + kbase + q * 8;
    #pragma unroll
    for (int kt = 0; kt < 8; kt++) Bp[nt][kt] = *(const short8*)(mb + kt * 32);
  }

  float hprev[4][4];
  #pragma unroll
  for (int a = 0; a < 4; a++)
    #pragma unroll
    for (int b = 0; b < 4; b++) hprev[a][b] = 0.f;

  const bool hasxp = (role == 0) && isCons;  // cols 0..255 get xp
  const float* xpb = xp + ((g * 16 + 4 * q) << 8) + w * 64 + n;
  float xpA[4][4], xpB[4][4];
  #pragma unroll
  for (int a = 0; a < 4; a++)
    #pragma unroll
    for (int b = 0; b < 4; b++) { xpA[a][b] = 0.f; xpB[a][b] = 0.f; }
  if (hasxp) {
    #pragma unroll
    for (int nt = 0; nt < 4; nt++)
      #pragma unroll
      for (int j = 0; j < 4; j++) {
        xpA[nt][j] = __builtin_nontemporal_load(xpb + 0L * 16384 + j * 256 + nt * 16);
        xpB[nt][j] = __builtin_nontemporal_load(xpb + 1L * 16384 + j * 256 + nt * 16);
      }
  }

  // exchange addressing
  char* xship = ws + WS_X + (((g * 2 + role) * 4 + wl) * 2) * 2048 + lane * 32;
  char* xrecv = ws + WS_X + (((g * 2 + (1 - role)) * 4 + wl) * 2) * 2048 + lane * 32;
  unsigned* fship = flags + ((g * 2 + role) * 4 + wl) * 16;
  unsigned* frecv = flags + ((g * 2 + (1 - role)) * 4 + wl) * 16;

  float* outb = out + (long)(g * 16 + 4 * q) * (NT * NH) + w * 64 + n;

  __syncthreads();
  const bool fastp = (sFast != 0);

  auto step = [&](const unsigned short* __restrict__ hr,
                  unsigned short* __restrict__ hw, int tt,
                  float (&xpc)[4][4]) {
    f32x4 acc[4];
    #pragma unroll
    for (int nt = 0; nt < 4; nt++) acc[nt] = (f32x4){0.f, 0.f, 0.f, 0.f};

    #pragma unroll
    for (int kt = 0; kt < 8; kt++) {
      unsigned e = (unsigned)((n * 256 + kt * 32 + q * 8) ^ ((n & 7) << 3));
      short8 a = *(const short8*)(hr + e);
      #pragma unroll
      for (int nt = 0; nt < 4; nt++) acc[nt] = mfma16(a, Bp[nt][kt], acc[nt]);
    }

    const int t = tt + 1;  // flag sequence number (flags start at 0)
    if (!isCons) {
      // ---- ship partials to partner ----
      unsigned pk[8];
      #pragma unroll
      for (int nt = 0; nt < 4; nt++) {
        asm("v_cvt_pk_bf16_f32 %0, %1, %2"
            : "=v"(pk[2 * nt]) : "v"(acc[nt][0]), "v"(acc[nt][1]));
        asm("v_cvt_pk_bf16_f32 %0, %1, %2"
            : "=v"(pk[2 * nt + 1]) : "v"(acc[nt][2]), "v"(acc[nt][3]));
      }
      char* xb = xship + (t & 1) * 2048;
      if (fastp) {
        uint4 v0 = {pk[0], pk[1], pk[2], pk[3]};
        uint4 v1 = {pk[4], pk[5], pk[6], pk[7]};
        *(uint4*)xb = v0;
        *(uint4*)(xb + 16) = v1;
        asm volatile("s_waitcnt vmcnt(0)" ::: "memory");
        if (lane == 0) *(volatile unsigned*)fship = (unsigned)t;
      } else {
        unsigned long long* xq = (unsigned long long*)xb;
        #pragma unroll
        for (int i = 0; i < 4; i++) {
          unsigned long long u =
              (unsigned long long)pk[2 * i] |
              ((unsigned long long)pk[2 * i + 1] << 32);
          __hip_atomic_store(xq + i, u, __ATOMIC_RELAXED, __HIP_MEMORY_SCOPE_AGENT);
        }
        if (lane == 0)
          __hip_atomic_store(fship, (unsigned)t, __ATOMIC_RELEASE,
                             __HIP_MEMORY_SCOPE_AGENT);
      }
    } else {
      // ---- consume partner partials, finalize own cols ----
      unsigned pk[8];
      const char* xb = xrecv + (t & 1) * 2048;
      if (fastp) {
        while (*(volatile const unsigned*)frecv < (unsigned)t)
          __builtin_amdgcn_s_sleep(1);
        volatile const unsigned* xv = (volatile const unsigned*)xb;
        #pragma unroll
        for (int i = 0; i < 8; i++) pk[i] = xv[i];
      } else {
        while (__hip_atomic_load(frecv, __ATOMIC_RELAXED,
                                 __HIP_MEMORY_SCOPE_AGENT) < (unsigned)t)
          __builtin_amdgcn_s_sleep(1);
        const unsigned long long* xq = (const unsigned long long*)xb;
        #pragma unroll
        for (int i = 0; i < 4; i++) {
          unsigned long long u =
              __hip_atomic_load(xq + i, __ATOMIC_RELAXED, __HIP_MEMORY_SCOPE_AGENT);
          pk[2 * i] = (unsigned)u;
          pk[2 * i + 1] = (unsigned)(u >> 32);
        }
      }
      float* outt = outb + tt * NH;
      int tn = tt + 2; if (tn >= NT) tn = 0;
      const float* xpl = xpb + (long)tn * 16384;
      #pragma unroll
      for (int nt = 0; nt < 4; nt++) {
        float p0 = bflo(pk[2 * nt]), p1 = bfhi(pk[2 * nt]);
        float p2 = bflo(pk[2 * nt + 1]), p3 = bfhi(pk[2 * nt + 1]);
        float s0 = acc[nt][0] + p0 + xpc[nt][0];
        float s1 = acc[nt][1] + p1 + xpc[nt][1];
        float s2 = acc[nt][2] + p2 + xpc[nt][2];
        float s3 = acc[nt][3] + p3 + xpc[nt][3];
        #pragma unroll
        for (int j = 0; j < 4; j++) {
          float s = (j == 0) ? s0 : (j == 1) ? s1 : (j == 2) ? s2 : s3;
          float v = fmaf(hprev[nt][j], C1, s);
          v = fmaxf(v, 0.f);
          hprev[nt][j] = v;
          __builtin_nontemporal_store(v, outt + (long)j * (NT * NH) + nt * 16);
          unsigned rr;
          asm("v_cvt_pk_bf16_f32 %0, %1, %2" : "=v"(rr) : "v"(v), "v"(v));
          int mm = 4 * q + j;
          int cl = wl * 64 + nt * 16 + n;  // local col in this k-half
          hw[(unsigned)((mm * 256 + cl) ^ ((mm & 7) << 3))] = (unsigned short)rr;
          if (hasxp)
            xpc[nt][j] = __builtin_nontemporal_load(xpl + j * 256 + nt * 16);
        }
      }
    }
    asm volatile("s_waitcnt lgkmcnt(0)\n\ts_barrier" ::: "memory");
  };

  #pragma unroll 1
  for (int tt = 0; tt < NT; tt += 2) {
    step(hb[0], hb[1], tt, xpA);
    step(hb[1], hb[0], tt + 1, xpB);
  }

  // final h1, h2 (consume waves own the finalized cols)
  if (isCons) {
    const long fbase = (long)NB * NT * NH;
    #pragma unroll
    for (int nt = 0; nt < 4; nt++) {
      #pragma unroll
      for (int j = 0; j < 4; j++) {
        int b = g * 16 + 4 * q + j;
        int col = w * 64 + nt * 16 + n;
        long off = (col < 256) ? (fbase + b * 256 + col)
                               : (fbase + 16384 + b * 256 + (col - 256));
        out[off] = hprev[nt][j];
      }
    }
  }
}

extern "C" void kernel_launch(void* const* d_in, const int* in_sizes, int n_in,
                              void* d_out, int out_size, void* d_ws, size_t ws_size,
                              hipStream_t stream) {
  const float* x   = (const float*)d_in[0];
  const float* Wi  = (const float*)d_in[2];
  const float* bi  = (const float*)d_in[3];
  const float* W11 = (const float*)d_in[4];
  const float* W22 = (const float*)d_in[5];
  const float* W12 = (const float*)d_in[6];
  const float* W21 = (const float*)d_in[7];
  float* out = (float*)d_out;

  unsigned short* M = (unsigned short*)d_ws;
  float* WiT = (float*)((char*)d_ws + 524288);
  unsigned* ctrl = (unsigned*)((char*)d_ws + WS_FLAGS);
  float* xp = (float*)((char*)d_ws + WS_XP);

  buildM_k<<<1024, 256, 0, stream>>>(W11, W22, W12, W21, M, ctrl);
  buildWiT_k<<<128, 256, 0, stream>>>(Wi, WiT);
  xproj_k<<<1024, 256, 0, stream>>>(x, WiT, bi, xp);
  rnn_k<<<16, 512, 0, stream>>>(M, xp, out, (char*)d_ws);
}